// Round 7
// baseline (27.100 us; speedup 1.0000x reference)
//
#include <hip/hip_runtime.h>

// ConduitHydrology on a static 1500x1500 raster.
// Link layout: horizontal id = r*(NCOLS-1)+c (tail (r,c) -> head (r,c+1)),
//              vertical   id = NH + r*NCOLS+c (tail (r,c) -> head (r+1,c)).
// link_length constant DX=100 (folded); head/tail implied by raster layout.
// Interior fast path: ne == eff, cnt == 4, center cancels: sum_grad=(E-W)+(S-N).
//
// R6 structure: 2 rows x 4 cols per thread (16B lane stride preserved —
// R4's 32B stride regressed). Block (64,8)=512 threads covers 256 x 16.
// eff rows reused in-register across the vertical pair; ~2x loads in
// flight per wave. GX=6, GY=94, NWG=564; bijective XCD swizzle (q=70,r=4).
// R5 OOB bug fixed: c0 guard restored.

#define NROWS 1500
#define NCOLS 1500
#define NH    (NROWS * (NCOLS - 1))
#define GX    6
#define GY    94
#define NWG   (GX * GY)                // 564

#define OPENING_COEFF 1.3455e-09f
#define CLOSURE_COEFF 7.11e-24f
#define INV_SCALE_CUTOFF (1.0f / 5.74f)
#define STEP_HEIGHT 0.03f
#define INV_SEC_PER_A (1.0f / 31556926.0f)
#define INV_DX 0.01f

__device__ __forceinline__ float finish_node(float sum_grad, float sum_sv, float rcnt,
                                             float ne_c, float q, float g_geom)
{
    const float gradient = sum_grad * (INV_DX * rcnt) + g_geom;
    const float cavity   = fabsf(sum_sv * rcnt) * (STEP_HEIGHT * INV_SEC_PER_A);
    const float num = OPENING_COEFF * q * gradient + cavity;
    const float den = cavity * INV_SCALE_CUTOFF + CLOSURE_COEFF * ne_c * ne_c * ne_c;
    float conduit = num * __builtin_amdgcn_rcpf(den);
    conduit = (conduit < 1e-6f) ? 1e-6f : conduit;
    // conduit >= 1e-6 > 0: pow(x,1.25) == exp2(1.25*log2(x))
    const float p125 = __builtin_amdgcn_exp2f(1.25f * __builtin_amdgcn_logf(conduit));
    const float ag   = fabsf(gradient);
    return q - OPENING_COEFF * p125 * (gradient * __builtin_amdgcn_rsqf(ag));
}

__device__ __forceinline__ float slow_node(const float* __restrict__ eff,
                                           const float* __restrict__ discharge,
                                           const float* __restrict__ geom,
                                           const float* __restrict__ over,
                                           const float* __restrict__ sv,
                                           const int*   __restrict__ status,
                                           int r, int c)
{
    const int j0 = r * NCOLS + c;
    const float ne_c = status[j0] != 0 ? over[j0] : eff[j0];
    float sum_grad = 0.0f, sum_sv = 0.0f;
    if (c > 0) {
        const int j = j0 - 1;
        const float ne = status[j] != 0 ? over[j] : eff[j];
        sum_grad += (ne_c - ne);
        sum_sv   += sv[r * (NCOLS - 1) + (c - 1)];
    }
    if (c < NCOLS - 1) {
        const int j = j0 + 1;
        const float ne = status[j] != 0 ? over[j] : eff[j];
        sum_grad += (ne - ne_c);
        sum_sv   += sv[r * (NCOLS - 1) + c];
    }
    if (r > 0) {
        const int j = j0 - NCOLS;
        const float ne = status[j] != 0 ? over[j] : eff[j];
        sum_grad += (ne_c - ne);
        sum_sv   += sv[NH + (r - 1) * NCOLS + c];
    }
    if (r < NROWS - 1) {
        const int j = j0 + NCOLS;
        const float ne = status[j] != 0 ? over[j] : eff[j];
        sum_grad += (ne - ne_c);
        sum_sv   += sv[NH + r * NCOLS + c];
    }
    const int cnt = (c > 0) + (c < NCOLS - 1) + (r > 0) + (r < NROWS - 1);
    const float rcnt = (cnt == 4) ? 0.25f : ((cnt == 3) ? (1.0f / 3.0f) : 0.5f);
    return finish_node(sum_grad, sum_sv, rcnt, ne_c, discharge[j0], geom[j0]);
}

__global__ __launch_bounds__(512)
void conduit_kernel(const float* __restrict__ eff,
                    const float* __restrict__ discharge,
                    const float* __restrict__ geom,
                    const float* __restrict__ over,
                    const float* __restrict__ sv,
                    const int*   __restrict__ status,
                    float* __restrict__ out)
{
    // bijective XCD chunk swizzle: nwg=564, 8 XCDs -> q=70, rem=4
    const int orig = blockIdx.x;
    const int xcd  = orig & 7;
    const int base = orig >> 3;
    const int lin  = (xcd < 4) ? xcd * 71 + base
                               : 284 + (xcd - 4) * 70 + base;
    const int bx = lin % GX;           // col tile
    const int by = lin / GX;           // row tile (contiguous band per XCD)

    const int c0 = bx * 256 + threadIdx.x * 4;
    const int r0 = by * 16 + threadIdx.y * 2;
    if (c0 >= NCOLS || r0 >= NROWS) return;

    const bool interior = (r0 >= 2) && (r0 <= NROWS - 4) && (c0 >= 4) && (c0 <= NCOLS - 8);

    if (interior) {
        const int i0 = r0 * NCOLS + c0;
        const int i1 = i0 + NCOLS;
        // eff rows r0-1 .. r0+2 (shared across the vertical pair)
        const float4 eA = *(const float4*)(eff + i0 - NCOLS);
        const float4 e0 = *(const float4*)(eff + i0);
        const float4 e1 = *(const float4*)(eff + i1);
        const float4 e2 = *(const float4*)(eff + i1 + NCOLS);
        const float  eW0 = eff[i0 - 1], eE0 = eff[i0 + 4];
        const float  eW1 = eff[i1 - 1], eE1 = eff[i1 + 4];
        const float4 q0 = *(const float4*)(discharge + i0);
        const float4 q1 = *(const float4*)(discharge + i1);
        const float4 g0 = *(const float4*)(geom + i0);
        const float4 g1 = *(const float4*)(geom + i1);
        // vertical links: row k connects node rows k,k+1
        const float4 vA = *(const float4*)(sv + NH + (r0 - 1) * NCOLS + c0); // N of r0
        const float4 v0 = *(const float4*)(sv + NH + r0 * NCOLS + c0);       // S of r0 / N of r0+1
        const float4 v1 = *(const float4*)(sv + NH + (r0 + 1) * NCOLS + c0); // S of r0+1
        // horizontal links c0-1 .. c0+3 for both rows
        const int hb0 = r0 * (NCOLS - 1) + c0 - 1;
        const int hb1 = hb0 + (NCOLS - 1);
        const float a0 = sv[hb0], a1 = sv[hb0 + 1], a2 = sv[hb0 + 2],
                    a3 = sv[hb0 + 3], a4 = sv[hb0 + 4];
        const float b0 = sv[hb1], b1 = sv[hb1 + 1], b2 = sv[hb1 + 2],
                    b3 = sv[hb1 + 3], b4 = sv[hb1 + 4];

        float4 res0, res1;
        res0.x = finish_node((e0.y - eW0)  + (e1.x - eA.x), a0 + a1 + vA.x + v0.x,
                             0.25f, e0.x, q0.x, g0.x);
        res0.y = finish_node((e0.z - e0.x) + (e1.y - eA.y), a1 + a2 + vA.y + v0.y,
                             0.25f, e0.y, q0.y, g0.y);
        res0.z = finish_node((e0.w - e0.y) + (e1.z - eA.z), a2 + a3 + vA.z + v0.z,
                             0.25f, e0.z, q0.z, g0.z);
        res0.w = finish_node((eE0 - e0.z)  + (e1.w - eA.w), a3 + a4 + vA.w + v0.w,
                             0.25f, e0.w, q0.w, g0.w);
        res1.x = finish_node((e1.y - eW1)  + (e2.x - e0.x), b0 + b1 + v0.x + v1.x,
                             0.25f, e1.x, q1.x, g1.x);
        res1.y = finish_node((e1.z - e1.x) + (e2.y - e0.y), b1 + b2 + v0.y + v1.y,
                             0.25f, e1.y, q1.y, g1.y);
        res1.z = finish_node((e1.w - e1.y) + (e2.z - e0.z), b2 + b3 + v0.z + v1.z,
                             0.25f, e1.z, q1.z, g1.z);
        res1.w = finish_node((eE1 - e1.z)  + (e2.w - e0.w), b3 + b4 + v0.w + v1.w,
                             0.25f, e1.w, q1.w, g1.w);
        *(float4*)(out + i0) = res0;
        *(float4*)(out + i1) = res1;
    } else {
        // rim-adjacent / ragged-edge slow path: full per-node logic
        #pragma unroll
        for (int dr = 0; dr < 2; ++dr) {
            const int r = r0 + dr;
            if (r >= NROWS) break;
            #pragma unroll
            for (int k = 0; k < 4; ++k) {
                const int c = c0 + k;
                if (c >= NCOLS) break;
                out[r * NCOLS + c] = slow_node(eff, discharge, geom, over, sv, status, r, c);
            }
        }
    }
}

extern "C" void kernel_launch(void* const* d_in, const int* in_sizes, int n_in,
                              void* d_out, int out_size, void* d_ws, size_t ws_size,
                              hipStream_t stream) {
    const float* eff       = (const float*)d_in[0];
    const float* discharge = (const float*)d_in[1];
    const float* geom      = (const float*)d_in[2];
    const float* over      = (const float*)d_in[3];
    const float* sv        = (const float*)d_in[4];
    // d_in[5]=link_length constant; d_in[6]=head, d_in[7]=tail implied
    const int*   status    = (const int*)d_in[8];
    float* out = (float*)d_out;

    dim3 block(64, 8, 1);
    dim3 grid(NWG, 1, 1);
    conduit_kernel<<<grid, block, 0, stream>>>(eff, discharge, geom, over, sv, status, out);
}

// Round 8
// 18.142 us; speedup vs baseline: 1.4938x; 1.4938x over previous
//
#include <hip/hip_runtime.h>

// ConduitHydrology on a static 1500x1500 raster.
// Link layout: horizontal id = r*(NCOLS-1)+c (tail (r,c) -> head (r,c+1)),
//              vertical   id = NH + r*NCOLS+c (tail (r,c) -> head (r+1,c)).
// link_length constant DX=100 (folded); head/tail implied by raster layout.
// Interior fast path: ne == eff, cnt == 4, center cancels: sum_grad=(E-W)+(S-N).
//
// R7 probe: MAX-TLP. 2 cols/thread (float2), block (128,4)=512 threads
// covering 256 cols x 4 rows. NWG=2250 -> 18000 waves (2.2x residency).
// All loads coalesced at 8B lane stride. Bijective XCD swizzle (q=281,r=2).

#define NROWS 1500
#define NCOLS 1500
#define NH    (NROWS * (NCOLS - 1))
#define GX    6
#define GY    375
#define NWG   (GX * GY)                // 2250

#define OPENING_COEFF 1.3455e-09f
#define CLOSURE_COEFF 7.11e-24f
#define INV_SCALE_CUTOFF (1.0f / 5.74f)
#define STEP_HEIGHT 0.03f
#define INV_SEC_PER_A (1.0f / 31556926.0f)
#define INV_DX 0.01f

__device__ __forceinline__ float finish_node(float sum_grad, float sum_sv, float rcnt,
                                             float ne_c, float q, float g_geom)
{
    const float gradient = sum_grad * (INV_DX * rcnt) + g_geom;
    const float cavity   = fabsf(sum_sv * rcnt) * (STEP_HEIGHT * INV_SEC_PER_A);
    const float num = OPENING_COEFF * q * gradient + cavity;
    const float den = cavity * INV_SCALE_CUTOFF + CLOSURE_COEFF * ne_c * ne_c * ne_c;
    float conduit = num * __builtin_amdgcn_rcpf(den);
    conduit = (conduit < 1e-6f) ? 1e-6f : conduit;
    // conduit >= 1e-6 > 0: pow(x,1.25) == exp2(1.25*log2(x))
    const float p125 = __builtin_amdgcn_exp2f(1.25f * __builtin_amdgcn_logf(conduit));
    const float ag   = fabsf(gradient);
    return q - OPENING_COEFF * p125 * (gradient * __builtin_amdgcn_rsqf(ag));
}

__device__ __forceinline__ float slow_node(const float* __restrict__ eff,
                                           const float* __restrict__ discharge,
                                           const float* __restrict__ geom,
                                           const float* __restrict__ over,
                                           const float* __restrict__ sv,
                                           const int*   __restrict__ status,
                                           int r, int c)
{
    const int j0 = r * NCOLS + c;
    const float ne_c = status[j0] != 0 ? over[j0] : eff[j0];
    float sum_grad = 0.0f, sum_sv = 0.0f;
    if (c > 0) {
        const int j = j0 - 1;
        const float ne = status[j] != 0 ? over[j] : eff[j];
        sum_grad += (ne_c - ne);
        sum_sv   += sv[r * (NCOLS - 1) + (c - 1)];
    }
    if (c < NCOLS - 1) {
        const int j = j0 + 1;
        const float ne = status[j] != 0 ? over[j] : eff[j];
        sum_grad += (ne - ne_c);
        sum_sv   += sv[r * (NCOLS - 1) + c];
    }
    if (r > 0) {
        const int j = j0 - NCOLS;
        const float ne = status[j] != 0 ? over[j] : eff[j];
        sum_grad += (ne_c - ne);
        sum_sv   += sv[NH + (r - 1) * NCOLS + c];
    }
    if (r < NROWS - 1) {
        const int j = j0 + NCOLS;
        const float ne = status[j] != 0 ? over[j] : eff[j];
        sum_grad += (ne - ne_c);
        sum_sv   += sv[NH + r * NCOLS + c];
    }
    const int cnt = (c > 0) + (c < NCOLS - 1) + (r > 0) + (r < NROWS - 1);
    const float rcnt = (cnt == 4) ? 0.25f : ((cnt == 3) ? (1.0f / 3.0f) : 0.5f);
    return finish_node(sum_grad, sum_sv, rcnt, ne_c, discharge[j0], geom[j0]);
}

__global__ __launch_bounds__(512)
void conduit_kernel(const float* __restrict__ eff,
                    const float* __restrict__ discharge,
                    const float* __restrict__ geom,
                    const float* __restrict__ over,
                    const float* __restrict__ sv,
                    const int*   __restrict__ status,
                    float* __restrict__ out)
{
    // bijective XCD chunk swizzle: nwg=2250, 8 XCDs -> q=281, rem=2
    const int orig = blockIdx.x;
    const int xcd  = orig & 7;
    const int base = orig >> 3;
    const int lin  = (xcd < 2) ? xcd * 282 + base
                               : 2 * 282 + (xcd - 2) * 281 + base;
    const int bx = lin % GX;           // col tile
    const int by = lin / GX;           // row tile (contiguous band per XCD)

    const int c0 = bx * 256 + threadIdx.x * 2;
    const int r  = by * 4 + threadIdx.y;
    if (c0 >= NCOLS) return;
    const int idx = r * NCOLS + c0;

    const bool interior = (r >= 2) && (r <= NROWS - 3) && (c0 >= 2) && (c0 <= NCOLS - 4);

    if (interior) {
        const float2 eC = *(const float2*)(eff + idx);
        const float2 eN = *(const float2*)(eff + idx - NCOLS);
        const float2 eS = *(const float2*)(eff + idx + NCOLS);
        const float  eW = eff[idx - 1];
        const float  eE = eff[idx + 2];
        const float2 q2 = *(const float2*)(discharge + idx);
        const float2 g2 = *(const float2*)(geom + idx);
        const float2 vN = *(const float2*)(sv + NH + (r - 1) * NCOLS + c0);
        const float2 vS = *(const float2*)(sv + NH + r * NCOLS + c0);
        const int hb = r * (NCOLS - 1) + c0 - 1;   // horizontal links c0-1, c0, c0+1
        const float h0 = sv[hb], h1 = sv[hb + 1], h2 = sv[hb + 2];

        float2 res;
        res.x = finish_node((eC.y - eW) + (eS.x - eN.x), h0 + h1 + vN.x + vS.x,
                            0.25f, eC.x, q2.x, g2.x);
        res.y = finish_node((eE - eC.x) + (eS.y - eN.y), h1 + h2 + vN.y + vS.y,
                            0.25f, eC.y, q2.y, g2.y);
        *(float2*)(out + idx) = res;
    } else {
        // rim-adjacent slow path: full per-node logic
        #pragma unroll
        for (int k = 0; k < 2; ++k) {
            const int c = c0 + k;
            if (c >= NCOLS) break;
            out[r * NCOLS + c] = slow_node(eff, discharge, geom, over, sv, status, r, c);
        }
    }
}

extern "C" void kernel_launch(void* const* d_in, const int* in_sizes, int n_in,
                              void* d_out, int out_size, void* d_ws, size_t ws_size,
                              hipStream_t stream) {
    const float* eff       = (const float*)d_in[0];
    const float* discharge = (const float*)d_in[1];
    const float* geom      = (const float*)d_in[2];
    const float* over      = (const float*)d_in[3];
    const float* sv        = (const float*)d_in[4];
    // d_in[5]=link_length constant; d_in[6]=head, d_in[7]=tail implied
    const int*   status    = (const int*)d_in[8];
    float* out = (float*)d_out;

    dim3 block(128, 4, 1);
    dim3 grid(NWG, 1, 1);
    conduit_kernel<<<grid, block, 0, stream>>>(eff, discharge, geom, over, sv, status, out);
}